// Round 1
// baseline (6171.324 us; speedup 1.0000x reference)
//
#include <hip/hip_runtime.h>
#include <cstddef>

#define LANG 50257
#define EDIM 512
#define HDIM 1024
#define ADIM 512
#define SLEN 1024
#define NSTEP 25
#define TEMPF 10.0f
#define SOSIDX 1
#define VOFF (NSTEP * LANG)   // weights output offset in d_out

// ---------------- precompute P[s,a] = embeddings[s,:] @ W1[:A,:] + b1 --------
__global__ __launch_bounds__(256) void k_precompute_P(
    const float* __restrict__ emb_src, const float* __restrict__ W1,
    const float* __restrict__ b1, float* __restrict__ P) {
  __shared__ float se[8][ADIM];
  int s0 = blockIdx.x * 8;
  for (int i = threadIdx.x; i < 8 * ADIM; i += 256)
    se[i >> 9][i & 511] = emb_src[s0 * ADIM + i];
  __syncthreads();
  for (int a = threadIdx.x; a < ADIM; a += 256) {
    float acc[8];
#pragma unroll
    for (int i = 0; i < 8; ++i) acc[i] = b1[a];
    for (int k = 0; k < ADIM; ++k) {
      float wv = W1[k * ADIM + a];
#pragma unroll
      for (int i = 0; i < 8; ++i) acc[i] += se[i][k] * wv;
    }
#pragma unroll
    for (int i = 0; i < 8; ++i) P[(s0 + i) * ADIM + a] = acc[i];
  }
}

// ---------------- step-0 init: emb_acc = emb_T[SOS], denom = 1, h = hidden ---
__global__ __launch_bounds__(1024) void k_init(
    const float* __restrict__ emb_T, const float* __restrict__ hidden,
    float* __restrict__ emb_acc, float* __restrict__ h, float* __restrict__ denom) {
  int i = threadIdx.x;
  if (i < EDIM) emb_acc[i] = emb_T[SOSIDX * EDIM + i];
  h[i] = hidden[i];  // 1024 threads
  if (i == 0) denom[0] = 1.0f;
}

// ---------------- GRU cell: one wave per output j -----------------------------
__global__ __launch_bounds__(256) void k_gru(
    const float* __restrict__ W_ih, const float* __restrict__ W_hh,
    const float* __restrict__ b_ih, const float* __restrict__ b_hh,
    const float* __restrict__ emb_acc, const float* __restrict__ denomp,
    const float* __restrict__ h_old, float* __restrict__ h_new) {
  __shared__ float se[EDIM];
  __shared__ float sh[HDIM];
  float inv = 1.0f / denomp[0];
  for (int i = threadIdx.x; i < EDIM; i += 256) se[i] = emb_acc[i] * inv;
  for (int i = threadIdx.x; i < HDIM; i += 256) sh[i] = h_old[i];
  __syncthreads();
  int wave = threadIdx.x >> 6, lane = threadIdx.x & 63;
  int j = blockIdx.x * 4 + wave;  // 256 blocks * 4 waves = 1024
  float ir = 0.f, iz = 0.f, in_ = 0.f;
  for (int e = lane; e < EDIM; e += 64) {
    float x = se[e];
    ir  += W_ih[(size_t)j * EDIM + e] * x;
    iz  += W_ih[(size_t)(j + HDIM) * EDIM + e] * x;
    in_ += W_ih[(size_t)(j + 2 * HDIM) * EDIM + e] * x;
  }
  float hr = 0.f, hz = 0.f, hn = 0.f;
  for (int e = lane; e < HDIM; e += 64) {
    float x = sh[e];
    hr += W_hh[(size_t)j * HDIM + e] * x;
    hz += W_hh[(size_t)(j + HDIM) * HDIM + e] * x;
    hn += W_hh[(size_t)(j + 2 * HDIM) * HDIM + e] * x;
  }
#pragma unroll
  for (int off = 32; off; off >>= 1) {
    ir += __shfl_down(ir, off);  iz += __shfl_down(iz, off);  in_ += __shfl_down(in_, off);
    hr += __shfl_down(hr, off);  hz += __shfl_down(hz, off);  hn += __shfl_down(hn, off);
  }
  if (lane == 0) {
    float r = 1.f / (1.f + expf(-(ir + b_ih[j] + hr + b_hh[j])));
    float z = 1.f / (1.f + expf(-(iz + b_ih[j + HDIM] + hz + b_hh[j + HDIM])));
    float n = tanhf(in_ + b_ih[j + 2 * HDIM] + r * (hn + b_hh[j + 2 * HDIM]));
    h_new[j] = (1.f - z) * n + z * sh[j];
  }
}

// ---------------- hproj[a] = h_new @ W1[A:,a]; block 0 also resets emb_acc ----
__global__ __launch_bounds__(256) void k_hproj(
    const float* __restrict__ W1, const float* __restrict__ h,
    float* __restrict__ hproj, float* __restrict__ emb_acc) {
  __shared__ float sh[HDIM];
  for (int i = threadIdx.x; i < HDIM; i += 256) sh[i] = h[i];
  __syncthreads();
  int a = blockIdx.x * 256 + threadIdx.x;  // 2 blocks
  float acc = 0.f;
  for (int j = 0; j < HDIM; ++j) acc += sh[j] * W1[(size_t)(ADIM + j) * ADIM + a];
  hproj[a] = acc;
  if (blockIdx.x == 0) {  // reset feedback accumulator for this step's k_emb
    emb_acc[threadIdx.x] = 0.f;
    emb_acc[threadIdx.x + 256] = 0.f;
  }
}

// ---------------- scores[s] = v . tanh(P[s,:] + hproj) ------------------------
__global__ __launch_bounds__(256) void k_scores(
    const float* __restrict__ P, const float* __restrict__ hproj,
    const float* __restrict__ v, float* __restrict__ scores) {
  __shared__ float shp[ADIM], sv[ADIM];
  for (int i = threadIdx.x; i < ADIM; i += 256) { shp[i] = hproj[i]; sv[i] = v[i]; }
  __syncthreads();
  int wave = threadIdx.x >> 6, lane = threadIdx.x & 63;
  int s = blockIdx.x * 4 + wave;  // 256 blocks
  float acc = 0.f;
  for (int a = lane; a < ADIM; a += 64)
    acc += sv[a] * tanhf(P[(size_t)s * ADIM + a] + shp[a]);
#pragma unroll
  for (int off = 32; off; off >>= 1) acc += __shfl_down(acc, off);
  if (lane == 0) scores[s] = acc;
}

// ---------------- softmax over 1024 scores -> attention weights (to d_out) ---
__global__ __launch_bounds__(1024) void k_attn_softmax(
    const float* __restrict__ scores, float* __restrict__ w_out) {
  __shared__ float red[16];
  int tid = threadIdx.x;
  float x = scores[tid];
  float m = x;
#pragma unroll
  for (int off = 32; off; off >>= 1) m = fmaxf(m, __shfl_down(m, off));
  if ((tid & 63) == 0) red[tid >> 6] = m;
  __syncthreads();
  if (tid == 0) { float mm = red[0]; for (int i = 1; i < 16; ++i) mm = fmaxf(mm, red[i]); red[0] = mm; }
  __syncthreads();
  m = red[0];
  float e = expf(x - m);
  float ssum = e;
#pragma unroll
  for (int off = 32; off; off >>= 1) ssum += __shfl_down(ssum, off);
  __syncthreads();
  if ((tid & 63) == 0) red[tid >> 6] = ssum;
  __syncthreads();
  if (tid == 0) { float s = 0.f; for (int i = 0; i < 16; ++i) s += red[i]; red[0] = s; }
  __syncthreads();
  w_out[tid] = e / red[0];
}

// ---------------- attn[a] = sum_s w[s] * embeddings[s,a] ----------------------
__global__ __launch_bounds__(256) void k_attn_vec(
    const float* __restrict__ w, const float* __restrict__ emb_src,
    float* __restrict__ attn) {
  __shared__ float sw[SLEN];
  for (int i = threadIdx.x; i < SLEN; i += 256) sw[i] = w[i];
  __syncthreads();
  int a = blockIdx.x * 256 + threadIdx.x;  // 2 blocks
  float acc = 0.f;
  for (int s = 0; s < SLEN; ++s) acc += sw[s] * emb_src[(size_t)s * ADIM + a];
  attn[a] = acc;
}

// ---------------- logits: vect[l] = TEMP*(out_W[l,:].[h;attn] + out_b[l]) -----
__global__ __launch_bounds__(256) void k_logits(
    const float* __restrict__ W, const float* __restrict__ b,
    const float* __restrict__ h, const float* __restrict__ attn,
    float* __restrict__ vect_out) {
  __shared__ float sm[HDIM + ADIM];
  for (int i = threadIdx.x; i < HDIM; i += 256) sm[i] = h[i];
  for (int i = threadIdx.x; i < ADIM; i += 256) sm[HDIM + i] = attn[i];
  __syncthreads();
  int wave = threadIdx.x >> 6, lane = threadIdx.x & 63;
  int l = blockIdx.x * 4 + wave;
  if (l >= LANG) return;
  const float4* row = reinterpret_cast<const float4*>(W + (size_t)l * 1536);
  const float4* sm4 = reinterpret_cast<const float4*>(sm);
  float acc = 0.f;
#pragma unroll
  for (int k = 0; k < 6; ++k) {
    float4 a4 = row[lane + k * 64];
    float4 b4 = sm4[lane + k * 64];
    acc += a4.x * b4.x + a4.y * b4.y + a4.z * b4.z + a4.w * b4.w;
  }
#pragma unroll
  for (int off = 32; off; off >>= 1) acc += __shfl_down(acc, off);
  if (lane == 0) vect_out[l] = (acc + b[l]) * TEMPF;
}

// ---------------- single-block softmax reduce over 50257 logits ---------------
__global__ __launch_bounds__(1024) void k_softmax_reduce(
    const float* __restrict__ logits, float* __restrict__ denom,
    float* __restrict__ maxval) {
  __shared__ float red[16];
  int tid = threadIdx.x;
  float m = -3.4e38f;
  for (int l = tid; l < LANG; l += 1024) m = fmaxf(m, logits[l]);
#pragma unroll
  for (int off = 32; off; off >>= 1) m = fmaxf(m, __shfl_down(m, off));
  if ((tid & 63) == 0) red[tid >> 6] = m;
  __syncthreads();
  if (tid == 0) { float mm = red[0]; for (int i = 1; i < 16; ++i) mm = fmaxf(mm, red[i]); red[0] = mm; }
  __syncthreads();
  m = red[0];
  float s = 0.f;
  for (int l = tid; l < LANG; l += 1024) s += expf(logits[l] - m);
#pragma unroll
  for (int off = 32; off; off >>= 1) s += __shfl_down(s, off);
  __syncthreads();
  if ((tid & 63) == 0) red[tid >> 6] = s;
  __syncthreads();
  if (tid == 0) {
    float ss = 0.f;
    for (int i = 0; i < 16; ++i) ss += red[i];
    denom[0] = ss;
    maxval[0] = m;
  }
}

// ---------------- emb_acc[e] += sum_l exp(logit[l]-max) * emb_T[l,e] ----------
__global__ __launch_bounds__(256) void k_emb(
    const float* __restrict__ logits, const float* __restrict__ emb_T,
    const float* __restrict__ maxval, float* __restrict__ emb_acc) {
  __shared__ float sp[128];
  int l0 = blockIdx.x * 128;  // 393 blocks
  float mv = maxval[0];
  for (int r = threadIdx.x; r < 128; r += 256) {
    int l = l0 + r;
    sp[r] = (l < LANG) ? expf(logits[l] - mv) : 0.f;
  }
  __syncthreads();
  float acc0 = 0.f, acc1 = 0.f;
  int rmax = (l0 + 128 <= LANG) ? 128 : (LANG - l0);
  for (int r = 0; r < rmax; ++r) {
    float p = sp[r];
    float2 v = reinterpret_cast<const float2*>(emb_T + (size_t)(l0 + r) * EDIM)[threadIdx.x];
    acc0 += p * v.x;
    acc1 += p * v.y;
  }
  atomicAdd(&emb_acc[2 * threadIdx.x], acc0);
  atomicAdd(&emb_acc[2 * threadIdx.x + 1], acc1);
}

extern "C" void kernel_launch(void* const* d_in, const int* in_sizes, int n_in,
                              void* d_out, int out_size, void* d_ws, size_t ws_size,
                              hipStream_t stream) {
  const float* hidden   = (const float*)d_in[0];
  const float* emb_src  = (const float*)d_in[1];
  const float* emb_T    = (const float*)d_in[2];
  const float* W_ih     = (const float*)d_in[3];
  const float* W_hh     = (const float*)d_in[4];
  const float* b_ih     = (const float*)d_in[5];
  const float* b_hh     = (const float*)d_in[6];
  const float* attn_W1  = (const float*)d_in[7];
  const float* attn_b1  = (const float*)d_in[8];
  const float* attn_v   = (const float*)d_in[9];
  const float* out_W    = (const float*)d_in[10];
  const float* out_b    = (const float*)d_in[11];
  float* out = (float*)d_out;
  float* ws  = (float*)d_ws;

  // ws layout (floats)
  float* P       = ws;                  // 1024*512 = 524288
  float* emb_acc = ws + 524288;         // 512
  float* hbuf    = ws + 524800;         // 2*1024
  float* hproj   = ws + 526848;         // 512
  float* scores  = ws + 527360;         // 1024
  float* attn    = ws + 528384;         // 512
  float* denom   = ws + 528896;         // 1
  float* maxval  = ws + 528897;         // 1

  k_precompute_P<<<128, 256, 0, stream>>>(emb_src, attn_W1, attn_b1, P);
  k_init<<<1, 1024, 0, stream>>>(emb_T, hidden, emb_acc, hbuf, denom);

  for (int t = 0; t < NSTEP; ++t) {
    const float* h_old = hbuf + (t & 1) * HDIM;
    float* h_new       = hbuf + ((t + 1) & 1) * HDIM;
    k_gru<<<256, 256, 0, stream>>>(W_ih, W_hh, b_ih, b_hh, emb_acc, denom, h_old, h_new);
    k_hproj<<<2, 256, 0, stream>>>(attn_W1, h_new, hproj, emb_acc);
    k_scores<<<256, 256, 0, stream>>>(P, hproj, attn_v, scores);
    float* w_out = out + VOFF + (size_t)t * SLEN;
    k_attn_softmax<<<1, 1024, 0, stream>>>(scores, w_out);
    k_attn_vec<<<2, 256, 0, stream>>>(w_out, emb_src, attn);
    float* vect = out + (size_t)t * LANG;
    k_logits<<<(LANG + 3) / 4, 256, 0, stream>>>(out_W, out_b, h_new, attn, vect);
    if (t + 1 < NSTEP) {
      k_softmax_reduce<<<1, 1024, 0, stream>>>(vect, denom, maxval);
      k_emb<<<(LANG + 127) / 128, 256, 0, stream>>>(vect, emb_T, maxval, emb_acc);
    }
  }
}